// Round 8
// baseline (332.848 us; speedup 1.0000x reference)
//
#include <hip/hip_runtime.h>
#include <hip/hip_bf16.h>
#include <hip/hip_cooperative_groups.h>
#include <math.h>

namespace cg = cooperative_groups;

#define L 252
#define HID 768
#define MLP 770
#define NLAB 36
#define NB 2
#define M1 (NB*L)         // 504
#define N1 (2*MLP)        // 1540
#define LL (L*L)          // 63504
#define LL4 (LL/4)        // 15876
#define KC 25             // main K chunks (800 = 25*32)
#define KC1 24            // gemm1 K chunks (768 = 24*32)
#define NT1P 100          // W1F n-tiles
#define NMT 32            // VBF m-tiles
#define GRID 504

typedef float f32x4 __attribute__((ext_vector_type(4)));
typedef short short8 __attribute__((ext_vector_type(8)));

// ---- ws layout (floats) ----
#define AJF_OFF 0                               // bf16 [2][25][16 jt][64][8]
#define AJF_FLOATS 204800
#define AIB_OFF (AJF_OFF + AJF_FLOATS)          // bf16 [3][504][800]
#define AIB_FLOATS 604800
#define W2F_OFF (AIB_OFF + AIB_FLOATS)          // uint4 [25][3][64]
#define W2F_FLOATS 19200
#define PART_OFF (W2F_OFF + W2F_FLOATS)         // float2 [72][1024]
#define PART_FLOATS (72*1024*2)
#define W1F_OFF (PART_OFF + PART_FLOATS)        // uint4 [24][100][64]
#define W1F_FLOATS (KC1*NT1P*64*4)
#define VBF_OFF (W1F_OFF + W1F_FLOATS)          // uint4 [32 mt][24 kc][64]
#define VBF_FLOATS (NMT*KC1*64*4)
#define NW1F (KC1*NT1P*64)
#define NW2F (KC*3*64)
#define NVBF (NMT*KC1*64)

__device__ __forceinline__ void dma16(const void* g, void* l) {
  __builtin_amdgcn_global_load_lds(
      (const __attribute__((address_space(1))) unsigned int*)g,
      (__attribute__((address_space(3))) unsigned int*)l, 16, 0, 0);
}

__device__ __forceinline__ unsigned short bf16b(float x) {
  __hip_bfloat16 h = __float2bfloat16(x);
  return *reinterpret_cast<unsigned short*>(&h);
}

// gfx9 s_waitcnt imm: vmcnt[3:0] | expcnt<<4 | lgkmcnt<<8 | vmcnt_hi<<14
#define WAIT_VM0() __builtin_amdgcn_s_waitcnt(0x0F70)   // vmcnt(0)
#define WAIT_VM5() __builtin_amdgcn_s_waitcnt(0x0F75)   // vmcnt(5)

__global__ __launch_bounds__(256, 2) void mega_kernel(
    const float* __restrict__ hid, const int* __restrict__ spans,
    const int* __restrict__ smask, const float* __restrict__ W1,
    const float* __restrict__ b1, const float* __restrict__ W2,
    const float* __restrict__ b2, float* __restrict__ ws,
    float* __restrict__ out) {
  cg::grid_group grid = cg::this_grid();
  __shared__ char sm[61440];
  int t = threadIdx.x;
  int blk = blockIdx.x;
  int wave = t >> 6, lane = t & 63, lj = lane & 15, kh = lane >> 4;

  unsigned short* AJF  = (unsigned short*)(ws + AJF_OFF);
  unsigned short* AiBh = (unsigned short*)(ws + AIB_OFF);
  uint4* W2F           = (uint4*)(ws + W2F_OFF);
  float* part          = ws + PART_OFF;

  // ======================= Phase P: pack =======================
  {
    const int total = NW1F + NW2F + NVBF;
    for (int idx = blk * 256 + t; idx < total; idx += GRID * 256) {
      if (idx < NW1F) {
        int kc = idx / (NT1P * 64);
        int rem = idx - kc * (NT1P * 64);
        int nt = rem / 64, ln = rem - nt * 64;
        int n = nt * 16 + (ln & 15);
        int kb = kc * 32 + (ln >> 4) * 8;
        unsigned int u[4];
#pragma unroll
        for (int p = 0; p < 4; p++) {
          unsigned short us[2];
#pragma unroll
          for (int q = 0; q < 2; q++) {
            int k = kb + 2 * p + q;
            float v = 0.f;
            if (n < N1) v = (n < MLP) ? W1[(size_t)n * 1537 + k]
                                      : W1[(size_t)(n - MLP) * 1537 + HID + k];
            us[q] = bf16b(v);
          }
          u[p] = (unsigned int)us[0] | ((unsigned int)us[1] << 16);
        }
        ((uint4*)(ws + W1F_OFF))[idx] = make_uint4(u[0], u[1], u[2], u[3]);
      } else if (idx < NW1F + NW2F) {
        int e2 = idx - NW1F;
        int kc = e2 / 192, rem = e2 - kc * 192;
        int tile = rem / 64, ln = rem - tile * 64;
        int label = tile * 16 + (ln & 15);
        int kb = kc * 32 + (ln >> 4) * 8;
        unsigned int u[4];
#pragma unroll
        for (int p = 0; p < 4; p++) {
          unsigned short us[2];
#pragma unroll
          for (int q = 0; q < 2; q++) {
            int k = kb + 2 * p + q;
            float v = (label < NLAB && k < MLP) ? W2[label * MLP + k] : 0.f;
            us[q] = bf16b(v);
          }
          u[p] = (unsigned int)us[0] | ((unsigned int)us[1] << 16);
        }
        W2F[e2] = make_uint4(u[0], u[1], u[2], u[3]);
      } else {
        int e3 = idx - NW1F - NW2F;
        int mt = e3 / (KC1 * 64);
        int rem = e3 - mt * (KC1 * 64);
        int kc = rem / 64, ln = rem - kc * 64;
        int m = mt * 16 + (ln & 15);
        int kb = kc * 32 + (ln >> 4) * 8;
        unsigned int u[4] = {0u, 0u, 0u, 0u};
        if (m < M1) {
          int b = (m >= L) ? 1 : 0;
          const float* src = hid + ((size_t)(b * (L + 1) + 1 + (m - b * L))) * HID + kb;
          float4 v0 = *(const float4*)src;
          float4 v1 = *(const float4*)(src + 4);
          float vv[8] = {v0.x, v0.y, v0.z, v0.w, v1.x, v1.y, v1.z, v1.w};
#pragma unroll
          for (int p = 0; p < 4; p++)
            u[p] = (unsigned int)bf16b(vv[2 * p]) | ((unsigned int)bf16b(vv[2 * p + 1]) << 16);
        }
        ((uint4*)(ws + VBF_OFF))[e3] = make_uint4(u[0], u[1], u[2], u[3]);
      }
    }
  }
  grid.sync();

  // ======================= Phase G: gemm1 =======================
  if (blk < 200) {
    int gx = blk % 25, gy = blk / 25;
    int nt0 = gx * 4;
    int mt = gy * 4 + wave;
    int m0 = mt * 16;
    const uint4* vbf = (const uint4*)(ws + VBF_OFF) + (size_t)mt * KC1 * 64 + lane;
    const uint4* w1f = (const uint4*)(ws + W1F_OFF);
    char* WB = sm + wave * 15360;
    char* bA = WB;
    char* bB = WB + 5120;
    char* bC = WB + 10240;

    f32x4 acc[4];
#pragma unroll
    for (int nt = 0; nt < 4; nt++) acc[nt] = (f32x4)(0.f);
    union FU { unsigned u[4]; short8 s8; };

    dma16(vbf, bA);
#pragma unroll
    for (int q = 0; q < 4; q++)
      dma16(&w1f[(size_t)(0 * NT1P + nt0 + q) * 64 + lane], bA + 1024 + q * 1024);
    dma16(vbf + 64, bB);
#pragma unroll
    for (int q = 0; q < 4; q++)
      dma16(&w1f[(size_t)(1 * NT1P + nt0 + q) * 64 + lane], bB + 1024 + q * 1024);

    for (int kc = 0; kc < KC1; kc++) {
      WAIT_VM5();
      uint4 av = *(const uint4*)(bA + lane * 16);
      uint4 bv[4];
#pragma unroll
      for (int q = 0; q < 4; q++) bv[q] = *(const uint4*)(bA + 1024 + q * 1024 + lane * 16);
      __builtin_amdgcn_sched_barrier(0);
      int kn = kc + 2; if (kn > KC1 - 1) kn = KC1 - 1;
      dma16(vbf + kn * 64, bC);
#pragma unroll
      for (int q = 0; q < 4; q++)
        dma16(&w1f[(size_t)(kn * NT1P + nt0 + q) * 64 + lane], bC + 1024 + q * 1024);
      __builtin_amdgcn_sched_barrier(0);
      { char* tmp = bA; bA = bB; bB = bC; bC = tmp; }
      FU af; af.u[0] = av.x; af.u[1] = av.y; af.u[2] = av.z; af.u[3] = av.w;
#pragma unroll
      for (int q = 0; q < 4; q++) {
        FU bf; bf.u[0] = bv[q].x; bf.u[1] = bv[q].y; bf.u[2] = bv[q].z; bf.u[3] = bv[q].w;
        acc[q] = __builtin_amdgcn_mfma_f32_16x16x32_bf16(af.s8, bf.s8, acc[q], 0, 0, 0);
      }
    }
    WAIT_VM0();   // drain tail DMAs before LDS is reused by phase M

#pragma unroll
    for (int nt = 0; nt < 4; nt++) {
      int nn = (nt0 + nt) * 16 + lj;
      if (nn >= N1) continue;
      if (nn < MLP) {
        float b1v = b1[nn];
        float wv = W1[(size_t)nn * 1537 + 1536];
#pragma unroll
        for (int r = 0; r < 4; r++) {
          int mm = m0 + kh * 4 + r;
          if (mm < M1) {
            float a = acc[nt][r] + b1v;
            AiBh[(size_t)(0 * M1 + mm) * 800 + nn] = bf16b(a);
            AiBh[(size_t)(1 * M1 + mm) * 800 + nn] = bf16b(a + wv);
            AiBh[(size_t)(2 * M1 + mm) * 800 + nn] = bf16b(a + 2.f * wv);
          }
        }
      } else {
        int hh = nn - MLP;
        int kcq = hh >> 5, kk = hh & 31;
        int l2hi = (kk >> 3) << 4, ee = kk & 7;
#pragma unroll
        for (int r = 0; r < 4; r++) {
          int mm = m0 + kh * 4 + r;
          if (mm < M1) {
            int bb2 = (mm >= L) ? 1 : 0;
            int jg = mm - bb2 * L;
            size_t rec = ((size_t)((bb2 * KC + kcq) * 16 + (jg >> 4)) * 64 + (l2hi | (jg & 15)));
            AJF[rec * 8 + ee] = bf16b(acc[nt][r]);
          }
        }
      }
    }
  }
  grid.sync();

  // ======================= Phase M: main =======================
  {
    int mx_ = blk & 3;
    int my_ = (blk >> 2) % 63;
    int b = blk / 252;
    int j0 = mx_ * 64;
    int i0 = my_ * 4;
    int s = spans[2 * b], e = spans[2 * b + 1];
    int j = j0 + wave * 16 + lj;

    int poff[4];
#pragma unroll
    for (int ii = 0; ii < 4; ii++) {
      int i = i0 + ii;
      int ind = 0;
      if (i == s && j == e) ind = 2;
      else if (s <= i && i <= j && j <= e) ind = 1;
      poff[ii] = 1024 + ((ind * 4 + ii) * 4 + kh) * 16;
    }

    const unsigned short* aj_g = AJF + ((size_t)((b * KC + 0) * 16 + (j0 >> 4) + wave) * 64 + lane) * 8;
    int pr = lane >> 2; if (pr > 11) pr = 11;
    int pt = pr >> 2, pii = pr & 3, pc = lane & 3;
    const unsigned short* p_g = AiBh + (size_t)(pt * M1 + b * L + i0 + pii) * 800 + pc * 8;
    const uint4* wf_g = (const uint4*)W2F + lane;
    char* WB = sm + wave * 15360;
    char* bA = WB;
    char* bB = WB + 5120;
    char* bC = WB + 10240;

    f32x4 acc[4][3];
#pragma unroll
    for (int ii = 0; ii < 4; ii++)
#pragma unroll
      for (int tl = 0; tl < 3; tl++) acc[ii][tl] = (f32x4)(0.f);
    union FU { unsigned u[4]; short8 s8; };

    dma16(aj_g, bA);
    dma16(p_g, bA + 1024);
    dma16(&wf_g[0 * 64], bA + 2048);
    dma16(&wf_g[1 * 64], bA + 3072);
    dma16(&wf_g[2 * 64], bA + 4096);
    dma16(aj_g + 8192, bB);
    dma16(p_g + 32, bB + 1024);
    dma16(&wf_g[3 * 64], bB + 2048);
    dma16(&wf_g[4 * 64], bB + 3072);
    dma16(&wf_g[5 * 64], bB + 4096);

    for (int kc = 0; kc < KC; kc++) {
      WAIT_VM5();
      uint4 av = *(const uint4*)(bA + lane * 16);
      uint4 w0 = *(const uint4*)(bA + 2048 + lane * 16);
      uint4 w1 = *(const uint4*)(bA + 3072 + lane * 16);
      uint4 w2v = *(const uint4*)(bA + 4096 + lane * 16);
      uint4 pv[4];
#pragma unroll
      for (int ii = 0; ii < 4; ii++) pv[ii] = *(const uint4*)(bA + poff[ii]);
      __builtin_amdgcn_sched_barrier(0);
      int kn = kc + 2; if (kn > KC - 1) kn = KC - 1;
      dma16(aj_g + (size_t)kn * 8192, bC);
      dma16(p_g + kn * 32, bC + 1024);
      dma16(&wf_g[(kn * 3 + 0) * 64], bC + 2048);
      dma16(&wf_g[(kn * 3 + 1) * 64], bC + 3072);
      dma16(&wf_g[(kn * 3 + 2) * 64], bC + 4096);
      __builtin_amdgcn_sched_barrier(0);
      { char* tmp = bA; bA = bB; bB = bC; bC = tmp; }
      float ajf[8];
      ajf[0] = __uint_as_float(av.x << 16); ajf[1] = __uint_as_float(av.x & 0xFFFF0000u);
      ajf[2] = __uint_as_float(av.y << 16); ajf[3] = __uint_as_float(av.y & 0xFFFF0000u);
      ajf[4] = __uint_as_float(av.z << 16); ajf[5] = __uint_as_float(av.z & 0xFFFF0000u);
      ajf[6] = __uint_as_float(av.w << 16); ajf[7] = __uint_as_float(av.w & 0xFFFF0000u);
      FU wf0, wf1, wf2;
      wf0.u[0] = w0.x; wf0.u[1] = w0.y; wf0.u[2] = w0.z; wf0.u[3] = w0.w;
      wf1.u[0] = w1.x; wf1.u[1] = w1.y; wf1.u[2] = w1.z; wf1.u[3] = w1.w;
      wf2.u[0] = w2v.x; wf2.u[1] = w2v.y; wf2.u[2] = w2v.z; wf2.u[3] = w2v.w;
#pragma unroll
      for (int ii = 0; ii < 4; ii++) {
        unsigned pu[4] = {pv[ii].x, pv[ii].y, pv[ii].z, pv[ii].w};
        FU fr;
#pragma unroll
        for (int q = 0; q < 4; q++) {
          float x0 = fmaxf(ajf[2 * q] + __uint_as_float(pu[q] << 16), 0.f);
          float x1 = fmaxf(ajf[2 * q + 1] + __uint_as_float(pu[q] & 0xFFFF0000u), 0.f);
          __hip_bfloat162 pk = __float22bfloat162_rn(make_float2(x0, x1));
          fr.u[q] = *reinterpret_cast<unsigned*>(&pk);
        }
        acc[ii][0] = __builtin_amdgcn_mfma_f32_16x16x32_bf16(fr.s8, wf0.s8, acc[ii][0], 0, 0, 0);
        acc[ii][1] = __builtin_amdgcn_mfma_f32_16x16x32_bf16(fr.s8, wf1.s8, acc[ii][1], 0, 0, 0);
        acc[ii][2] = __builtin_amdgcn_mfma_f32_16x16x32_bf16(fr.s8, wf2.s8, acc[ii][2], 0, 0, 0);
      }
    }
    WAIT_VM0();   // drain tail DMAs before LDS reuse in phase F

    float v[4][3][4];
#pragma unroll
    for (int ii = 0; ii < 4; ii++) {
      int i = i0 + ii;
      int smv[4];
#pragma unroll
      for (int r = 0; r < 4; r++) {
        int jr = j0 + wave * 16 + kh * 4 + r;
        smv[r] = (jr < L) ? smask[(size_t)i * L + jr] : 0;
      }
#pragma unroll
      for (int tl = 0; tl < 3; tl++) {
        int label = tl * 16 + lj;
        bool lab_ok = label < NLAB;
        float bbv = lab_ok ? b2[label] : 0.f;
#pragma unroll
        for (int r = 0; r < 4; r++) {
          int jr = j0 + wave * 16 + kh * 4 + r;
          float vv = -1e30f;
          if (jr < L && lab_ok) {
            vv = (smv[r] >= 1) ? acc[ii][tl][r] + bbv : 0.f;
            out[(size_t)(b * NLAB + label) * LL + (size_t)i * L + jr] = vv;
          }
          v[ii][tl][r] = vv;
        }
      }
    }
#pragma unroll
    for (int tl = 0; tl < 3; tl++) {
      float mx = -1e30f;
#pragma unroll
      for (int ii = 0; ii < 4; ii++)
#pragma unroll
        for (int r = 0; r < 4; r++) mx = fmaxf(mx, v[ii][tl][r]);
      mx = fmaxf(mx, __shfl_xor(mx, 16, 64));
      mx = fmaxf(mx, __shfl_xor(mx, 32, 64));
      float ssum = 0.f;
#pragma unroll
      for (int ii = 0; ii < 4; ii++)
#pragma unroll
        for (int r = 0; r < 4; r++) {
          float vv = v[ii][tl][r];
          ssum += (vv > -1e29f) ? __expf(vv - mx) : 0.f;
        }
      ssum += __shfl_xor(ssum, 16, 64);
      ssum += __shfl_xor(ssum, 32, 64);
      int label = tl * 16 + lj;
      if (kh == 0 && label < NLAB) {
        int slot = (mx_ * 63 + my_) * 4 + wave;
        float2* pp = (float2*)part + (size_t)(b * NLAB + label) * 1024 + slot;
        *pp = make_float2(mx, ssum);
      }
    }
  }
  grid.sync();

  // ======================= Phase F: finish =======================
  {
    float* rm = (float*)sm;
    float* rs = rm + 4;
    float* lshp = rs + 4;
    for (int u = blk; u < 576; u += GRID) {
      int cx = u & 7, bk = u >> 3;
      const float2* pp = (const float2*)part + (size_t)bk * 1024;
      float m = -1e30f, ss = 0.f;
      for (int idx = t; idx < 1008; idx += 256) {
        float2 q = pp[idx];
        if (q.x > m) { ss = ss * __expf(m - q.x) + q.y; m = q.x; }
        else ss += q.y * __expf(q.x - m);
      }
#pragma unroll
      for (int o = 1; o < 64; o <<= 1) {
        float m2 = __shfl_xor(m, o, 64);
        float s2 = __shfl_xor(ss, o, 64);
        if (m2 > m) { ss = ss * __expf(m - m2) + s2; m = m2; }
        else ss += s2 * __expf(m2 - m);
      }
      if (lane == 0) { rm[wave] = m; rs[wave] = ss; }
      __syncthreads();
      if (t == 0) {
        float M = rm[0], S = rs[0];
#pragma unroll
        for (int w = 1; w < 4; w++) {
          float m2 = rm[w], s2 = rs[w];
          if (m2 > M) { S = S * __expf(M - m2) + s2; M = m2; }
          else S += s2 * __expf(m2 - M);
        }
        *lshp = M + logf(S);
      }
      __syncthreads();
      float l = *lshp;
      float4* po = (float4*)(out + (size_t)bk * LL);
      int start = cx * 1985;
      int end = start + 1985; if (end > LL4) end = LL4;
      for (int idx = start + t; idx < end; idx += 256) {
        float4 vv = po[idx];
        vv.x -= l; vv.y -= l; vv.z -= l; vv.w -= l;
        po[idx] = vv;
      }
      __syncthreads();
    }
  }
}

extern "C" void kernel_launch(void* const* d_in, const int* in_sizes, int n_in,
                              void* d_out, int out_size, void* d_ws, size_t ws_size,
                              hipStream_t stream) {
  const float* hidden = (const float*)d_in[0];
  const int* spans    = (const int*)d_in[1];
  const int* smask    = (const int*)d_in[2];
  const float* W1     = (const float*)d_in[3];
  const float* b1     = (const float*)d_in[4];
  const float* W2     = (const float*)d_in[5];
  const float* b2     = (const float*)d_in[6];
  float* ws  = (float*)d_ws;
  float* out = (float*)d_out;

  void* args[9] = {(void*)&hidden, (void*)&spans, (void*)&smask, (void*)&W1,
                   (void*)&b1, (void*)&W2, (void*)&b2, (void*)&ws, (void*)&out};
  hipLaunchCooperativeKernel((void*)mega_kernel, dim3(GRID), dim3(256), args, 0, stream);
}

// Round 10
// 133.803 us; speedup vs baseline: 2.4876x; 2.4876x over previous
//
#include <hip/hip_runtime.h>
#include <hip/hip_fp16.h>
#include <math.h>

#define L 252
#define HID 768
#define MLP 770
#define NLAB 36
#define NB 2
#define M1 (NB*L)         // 504
#define N1 (2*MLP)        // 1540
#define LL (L*L)          // 63504
#define LL4 (LL/4)        // 15876
#define KC 25             // main K chunks (800 = 25*32)
#define KC1 24            // gemm1 K chunks (768 = 24*32)
#define NT1P 100          // W1F n-tiles
#define NMT 32            // VBF m-tiles

typedef float f32x4 __attribute__((ext_vector_type(4)));
typedef _Float16 half8 __attribute__((ext_vector_type(8)));
typedef _Float16 half2v __attribute__((ext_vector_type(2)));

// ---- ws layout (floats) ----
#define AJF_OFF 0                               // fp16 [2][25][16 jt][64][8]
#define AJF_FLOATS 204800
#define AIB_OFF (AJF_OFF + AJF_FLOATS)          // fp16 [3][504][800]
#define AIB_FLOATS 604800
#define W2F_OFF (AIB_OFF + AIB_FLOATS)          // uint4 [25][3][64]
#define W2F_FLOATS 19200
#define PART_OFF (W2F_OFF + W2F_FLOATS)         // float2 [72][1024]
#define PART_FLOATS (72*1024*2)
#define W1F_OFF (PART_OFF + PART_FLOATS)        // uint4 [24][100][64]
#define W1F_FLOATS (KC1*NT1P*64*4)
#define VBF_OFF (W1F_OFF + W1F_FLOATS)          // uint4 [32 mt][24 kc][64]
#define VBF_FLOATS (NMT*KC1*64*4)
#define NW1F (KC1*NT1P*64)
#define NW2F (KC*3*64)
#define NVBF (NMT*KC1*64)

__device__ __forceinline__ void dma16(const void* g, void* l) {
  __builtin_amdgcn_global_load_lds(
      (const __attribute__((address_space(1))) unsigned int*)g,
      (__attribute__((address_space(3))) unsigned int*)l, 16, 0, 0);
}

__device__ __forceinline__ unsigned short f16b(float x) {
  _Float16 h = (_Float16)x;
  return *reinterpret_cast<unsigned short*>(&h);
}

// gfx9 s_waitcnt imm: vmcnt[3:0] | expcnt<<4 | lgkmcnt<<8 | vmcnt_hi<<14
#define WAIT_VM0() __builtin_amdgcn_s_waitcnt(0x0F70)   // vmcnt(0)
#define WAIT_VM5() __builtin_amdgcn_s_waitcnt(0x0F75)   // vmcnt(5)

// ---------------------------------------------------------------------------
// Pack: W1 -> W1F fp16 B-fragments; W2 -> W2F; hidden -> VBF fp16 A-fragments.
// ---------------------------------------------------------------------------
__global__ __launch_bounds__(256) void pack_kernel(const float* __restrict__ W1,
                                                   const float* __restrict__ W2,
                                                   const float* __restrict__ hid,
                                                   float* __restrict__ ws) {
  const int total = NW1F + NW2F + NVBF;
  int idx = blockIdx.x * 256 + threadIdx.x;
  if (idx >= total) return;
  if (idx < NW1F) {
    int kc = idx / (NT1P * 64);
    int rem = idx - kc * (NT1P * 64);
    int nt = rem / 64, lane = rem - nt * 64;
    int n = nt * 16 + (lane & 15);
    int kb = kc * 32 + (lane >> 4) * 8;
    unsigned int u[4];
#pragma unroll
    for (int p = 0; p < 4; p++) {
      unsigned short us[2];
#pragma unroll
      for (int q = 0; q < 2; q++) {
        int k = kb + 2 * p + q;
        float v = 0.f;
        if (n < N1) v = (n < MLP) ? W1[(size_t)n * 1537 + k]
                                  : W1[(size_t)(n - MLP) * 1537 + HID + k];
        us[q] = f16b(v);
      }
      u[p] = (unsigned int)us[0] | ((unsigned int)us[1] << 16);
    }
    ((uint4*)(ws + W1F_OFF))[idx] = make_uint4(u[0], u[1], u[2], u[3]);
  } else if (idx < NW1F + NW2F) {
    int e2 = idx - NW1F;
    int kc = e2 / 192, rem = e2 - kc * 192;
    int tile = rem / 64, lane = rem - tile * 64;
    int label = tile * 16 + (lane & 15);
    int kb = kc * 32 + (lane >> 4) * 8;
    unsigned int u[4];
#pragma unroll
    for (int p = 0; p < 4; p++) {
      unsigned short us[2];
#pragma unroll
      for (int q = 0; q < 2; q++) {
        int k = kb + 2 * p + q;
        float v = (label < NLAB && k < MLP) ? W2[label * MLP + k] : 0.f;
        us[q] = f16b(v);
      }
      u[p] = (unsigned int)us[0] | ((unsigned int)us[1] << 16);
    }
    ((uint4*)(ws + W2F_OFF))[e2] = make_uint4(u[0], u[1], u[2], u[3]);
  } else {
    int e3 = idx - NW1F - NW2F;
    int mt = e3 / (KC1 * 64);
    int rem = e3 - mt * (KC1 * 64);
    int kc = rem / 64, lane = rem - kc * 64;
    int m = mt * 16 + (lane & 15);
    int kb = kc * 32 + (lane >> 4) * 8;
    unsigned int u[4] = {0u, 0u, 0u, 0u};
    if (m < M1) {
      int b = (m >= L) ? 1 : 0;
      const float* src = hid + ((size_t)(b * (L + 1) + 1 + (m - b * L))) * HID + kb;
      float4 v0 = *(const float4*)src;
      float4 v1 = *(const float4*)(src + 4);
      float vv[8] = {v0.x, v0.y, v0.z, v0.w, v1.x, v1.y, v1.z, v1.w};
#pragma unroll
      for (int p = 0; p < 4; p++)
        u[p] = (unsigned int)f16b(vv[2 * p]) | ((unsigned int)f16b(vv[2 * p + 1]) << 16);
    }
    ((uint4*)(ws + VBF_OFF))[e3] = make_uint4(u[0], u[1], u[2], u[3]);
  }
}

// ---------------------------------------------------------------------------
// GEMM1: per-wave async pipeline, 2-ahead / 3 LDS buffers, vmcnt(5) waits.
// fp16 fragments, mfma_f32_16x16x32_f16. Buf: A[0,1K) B[1K,5K), 5KB each.
// ---------------------------------------------------------------------------
__global__ __launch_bounds__(256, 2) void gemm1_kernel(const float* __restrict__ b1,
                                                       const float* __restrict__ W1,
                                                       const float* __restrict__ ws_ro,
                                                       unsigned short* __restrict__ AJF,
                                                       unsigned short* __restrict__ AiBh) {
  __shared__ char sm[61440];
  int t = threadIdx.x;
  int wave = t >> 6, lane = t & 63, lj = lane & 15, kh = lane >> 4;
  int nt0 = blockIdx.x * 4;
  int mt = blockIdx.y * 4 + wave;
  int m0 = mt * 16;
  const uint4* vbf = (const uint4*)(ws_ro + VBF_OFF) + (size_t)mt * KC1 * 64 + lane;
  const uint4* w1f = (const uint4*)(ws_ro + W1F_OFF);
  char* WB = sm + wave * 15360;
  char* bA = WB;
  char* bB = WB + 5120;
  char* bC = WB + 10240;

  f32x4 acc[4];
#pragma unroll
  for (int nt = 0; nt < 4; nt++) acc[nt] = (f32x4)(0.f);
  union FU { unsigned u[4]; half8 h8; };

  dma16(vbf, bA);
#pragma unroll
  for (int q = 0; q < 4; q++)
    dma16(&w1f[(size_t)(0 * NT1P + nt0 + q) * 64 + lane], bA + 1024 + q * 1024);
  dma16(vbf + 64, bB);
#pragma unroll
  for (int q = 0; q < 4; q++)
    dma16(&w1f[(size_t)(1 * NT1P + nt0 + q) * 64 + lane], bB + 1024 + q * 1024);

  for (int kc = 0; kc < KC1; kc++) {
    WAIT_VM5();
    uint4 av = *(const uint4*)(bA + lane * 16);
    uint4 bv[4];
#pragma unroll
    for (int q = 0; q < 4; q++) bv[q] = *(const uint4*)(bA + 1024 + q * 1024 + lane * 16);
    __builtin_amdgcn_sched_barrier(0);
    int kn = kc + 2; if (kn > KC1 - 1) kn = KC1 - 1;
    dma16(vbf + kn * 64, bC);
#pragma unroll
    for (int q = 0; q < 4; q++)
      dma16(&w1f[(size_t)(kn * NT1P + nt0 + q) * 64 + lane], bC + 1024 + q * 1024);
    __builtin_amdgcn_sched_barrier(0);
    { char* tmp = bA; bA = bB; bB = bC; bC = tmp; }
    FU af; af.u[0] = av.x; af.u[1] = av.y; af.u[2] = av.z; af.u[3] = av.w;
#pragma unroll
    for (int q = 0; q < 4; q++) {
      FU bf; bf.u[0] = bv[q].x; bf.u[1] = bv[q].y; bf.u[2] = bv[q].z; bf.u[3] = bv[q].w;
      acc[q] = __builtin_amdgcn_mfma_f32_16x16x32_f16(af.h8, bf.h8, acc[q], 0, 0, 0);
    }
  }

#pragma unroll
  for (int nt = 0; nt < 4; nt++) {
    int nn = (nt0 + nt) * 16 + lj;
    if (nn >= N1) continue;
    if (nn < MLP) {
      float b1v = b1[nn];
      float wv = W1[(size_t)nn * 1537 + 1536];
#pragma unroll
      for (int r = 0; r < 4; r++) {
        int mm = m0 + kh * 4 + r;
        if (mm < M1) {
          float a = acc[nt][r] + b1v;
          AiBh[(size_t)(0 * M1 + mm) * 800 + nn] = f16b(a);
          AiBh[(size_t)(1 * M1 + mm) * 800 + nn] = f16b(a + wv);
          AiBh[(size_t)(2 * M1 + mm) * 800 + nn] = f16b(a + 2.f * wv);
        }
      }
    } else {
      int hh = nn - MLP;
      int kcq = hh >> 5, kk = hh & 31;
      int l2hi = (kk >> 3) << 4, ee = kk & 7;
#pragma unroll
      for (int r = 0; r < 4; r++) {
        int mm = m0 + kh * 4 + r;
        if (mm < M1) {
          int bb2 = (mm >= L) ? 1 : 0;
          int jg = mm - bb2 * L;
          size_t rec = ((size_t)((bb2 * KC + kcq) * 16 + (jg >> 4)) * 64 + (l2hi | (jg & 15)));
          AJF[rec * 8 + ee] = f16b(acc[nt][r]);
        }
      }
    }
  }
}

// ---------------------------------------------------------------------------
// Main: per-wave async pipeline, 2-ahead / 3 buffers, vmcnt(5). fp16 packed
// h-construction: v_pk_add_f16 + v_pk_max_f16 -> mfma_f16 (no repack).
// Block = 64j x 4i x b; wave = j-16-tile. Buf 5KB: aj[0,1K) p[1K,2K) wf[2K,5K).
// ---------------------------------------------------------------------------
__global__ __launch_bounds__(256, 2) void main_kernel(
    const unsigned short* __restrict__ AJF,
    const unsigned short* __restrict__ AiBh,
    const uint4* __restrict__ wfr,
    const float* __restrict__ b2,
    const int* __restrict__ spans,
    const int* __restrict__ smask,
    float* __restrict__ out,
    float* __restrict__ part) {
  __shared__ char sm[61440];
  int t = threadIdx.x;
  int wave = t >> 6, lane = t & 63, lj = lane & 15, kh = lane >> 4;
  int j0 = blockIdx.x * 64;
  int i0 = blockIdx.y * 4;
  int b = blockIdx.z;
  int s = spans[2 * b], e = spans[2 * b + 1];
  int j = j0 + wave * 16 + lj;

  int poff[4];
#pragma unroll
  for (int ii = 0; ii < 4; ii++) {
    int i = i0 + ii;
    int ind = 0;
    if (i == s && j == e) ind = 2;
    else if (s <= i && i <= j && j <= e) ind = 1;
    poff[ii] = 1024 + ((ind * 4 + ii) * 4 + kh) * 16;
  }

  const unsigned short* aj_g = AJF + ((size_t)((b * KC + 0) * 16 + (j0 >> 4) + wave) * 64 + lane) * 8;
  int pr = lane >> 2; if (pr > 11) pr = 11;
  int pt = pr >> 2, pii = pr & 3, pc = lane & 3;
  const unsigned short* p_g = AiBh + (size_t)(pt * M1 + b * L + i0 + pii) * 800 + pc * 8;
  const uint4* wf_g = wfr + lane;
  char* WB = sm + wave * 15360;
  char* bA = WB;
  char* bB = WB + 5120;
  char* bC = WB + 10240;

  f32x4 acc[4][3];
#pragma unroll
  for (int ii = 0; ii < 4; ii++)
#pragma unroll
    for (int tl = 0; tl < 3; tl++) acc[ii][tl] = (f32x4)(0.f);
  union FU { unsigned u[4]; half8 h8; };
  union U2 { unsigned u; half2v h; };

  dma16(aj_g, bA);
  dma16(p_g, bA + 1024);
  dma16(&wf_g[0 * 64], bA + 2048);
  dma16(&wf_g[1 * 64], bA + 3072);
  dma16(&wf_g[2 * 64], bA + 4096);
  dma16(aj_g + 8192, bB);
  dma16(p_g + 32, bB + 1024);
  dma16(&wf_g[3 * 64], bB + 2048);
  dma16(&wf_g[4 * 64], bB + 3072);
  dma16(&wf_g[5 * 64], bB + 4096);

  for (int kc = 0; kc < KC; kc++) {
    WAIT_VM5();
    uint4 av = *(const uint4*)(bA + lane * 16);
    uint4 w0 = *(const uint4*)(bA + 2048 + lane * 16);
    uint4 w1 = *(const uint4*)(bA + 3072 + lane * 16);
    uint4 w2v = *(const uint4*)(bA + 4096 + lane * 16);
    uint4 pv[4];
#pragma unroll
    for (int ii = 0; ii < 4; ii++) pv[ii] = *(const uint4*)(bA + poff[ii]);
    __builtin_amdgcn_sched_barrier(0);
    int kn = kc + 2; if (kn > KC - 1) kn = KC - 1;
    dma16(aj_g + (size_t)kn * 8192, bC);
    dma16(p_g + kn * 32, bC + 1024);
    dma16(&wf_g[(kn * 3 + 0) * 64], bC + 2048);
    dma16(&wf_g[(kn * 3 + 1) * 64], bC + 3072);
    dma16(&wf_g[(kn * 3 + 2) * 64], bC + 4096);
    __builtin_amdgcn_sched_barrier(0);
    { char* tmp = bA; bA = bB; bB = bC; bC = tmp; }
    unsigned avu[4] = {av.x, av.y, av.z, av.w};
    FU wf0, wf1, wf2;
    wf0.u[0] = w0.x; wf0.u[1] = w0.y; wf0.u[2] = w0.z; wf0.u[3] = w0.w;
    wf1.u[0] = w1.x; wf1.u[1] = w1.y; wf1.u[2] = w1.z; wf1.u[3] = w1.w;
    wf2.u[0] = w2v.x; wf2.u[1] = w2v.y; wf2.u[2] = w2v.z; wf2.u[3] = w2v.w;
#pragma unroll
    for (int ii = 0; ii < 4; ii++) {
      unsigned pu[4] = {pv[ii].x, pv[ii].y, pv[ii].z, pv[ii].w};
      FU fr;
#pragma unroll
      for (int q = 0; q < 4; q++) {
        U2 a, p, r;
        a.u = avu[q]; p.u = pu[q];
        half2v sum = a.h + p.h;                       // v_pk_add_f16
        half2v zz = (half2v)((_Float16)0);
        r.h = __builtin_elementwise_max(sum, zz);     // v_pk_max_f16
        fr.u[q] = r.u;
      }
      acc[ii][0] = __builtin_amdgcn_mfma_f32_16x16x32_f16(fr.h8, wf0.h8, acc[ii][0], 0, 0, 0);
      acc[ii][1] = __builtin_amdgcn_mfma_f32_16x16x32_f16(fr.h8, wf1.h8, acc[ii][1], 0, 0, 0);
      acc[ii][2] = __builtin_amdgcn_mfma_f32_16x16x32_f16(fr.h8, wf2.h8, acc[ii][2], 0, 0, 0);
    }
  }

  // Epilogue: masked store + fused softmax partials.
  float v[4][3][4];
#pragma unroll
  for (int ii = 0; ii < 4; ii++) {
    int i = i0 + ii;
    int smv[4];
#pragma unroll
    for (int r = 0; r < 4; r++) {
      int jr = j0 + wave * 16 + kh * 4 + r;
      smv[r] = (jr < L) ? smask[(size_t)i * L + jr] : 0;
    }
#pragma unroll
    for (int tl = 0; tl < 3; tl++) {
      int label = tl * 16 + lj;
      bool lab_ok = label < NLAB;
      float bbv = lab_ok ? b2[label] : 0.f;
#pragma unroll
      for (int r = 0; r < 4; r++) {
        int jr = j0 + wave * 16 + kh * 4 + r;
        float vv = -1e30f;
        if (jr < L && lab_ok) {
          vv = (smv[r] >= 1) ? acc[ii][tl][r] + bbv : 0.f;
          out[(size_t)(b * NLAB + label) * LL + (size_t)i * L + jr] = vv;
        }
        v[ii][tl][r] = vv;
      }
    }
  }
#pragma unroll
  for (int tl = 0; tl < 3; tl++) {
    float mx = -1e30f;
#pragma unroll
    for (int ii = 0; ii < 4; ii++)
#pragma unroll
      for (int r = 0; r < 4; r++) mx = fmaxf(mx, v[ii][tl][r]);
    mx = fmaxf(mx, __shfl_xor(mx, 16, 64));
    mx = fmaxf(mx, __shfl_xor(mx, 32, 64));
    float ssum = 0.f;
#pragma unroll
    for (int ii = 0; ii < 4; ii++)
#pragma unroll
      for (int r = 0; r < 4; r++) {
        float vv = v[ii][tl][r];
        ssum += (vv > -1e29f) ? __expf(vv - mx) : 0.f;
      }
    ssum += __shfl_xor(ssum, 16, 64);
    ssum += __shfl_xor(ssum, 32, 64);
    int label = tl * 16 + lj;
    if (kh == 0 && label < NLAB) {
      int slot = (blockIdx.x * 63 + blockIdx.y) * 4 + wave;
      float2* pp = (float2*)part + (size_t)(b * NLAB + label) * 1024 + slot;
      *pp = make_float2(mx, ssum);
    }
  }
}

// ---------------------------------------------------------------------------
// Finish: grid (8, 72). Each block reduces the 1008 partials of its (b,label)
// (L2-hot, redundant x8) to lse, then subtracts over its slice of out.
// ---------------------------------------------------------------------------
__global__ __launch_bounds__(256) void finish_kernel(const float* __restrict__ part,
                                                     float* __restrict__ out) {
  int bk = blockIdx.y, cx = blockIdx.x;
  int t = threadIdx.x, wave = t >> 6, lane = t & 63;
  const float2* pp = (const float2*)part + (size_t)bk * 1024;
  float m = -1e30f, ss = 0.f;
  for (int idx = t; idx < 1008; idx += 256) {
    float2 q = pp[idx];
    if (q.x > m) { ss = ss * __expf(m - q.x) + q.y; m = q.x; }
    else ss += q.y * __expf(q.x - m);
  }
#pragma unroll
  for (int o = 1; o < 64; o <<= 1) {
    float m2 = __shfl_xor(m, o, 64);
    float s2 = __shfl_xor(ss, o, 64);
    if (m2 > m) { ss = ss * __expf(m - m2) + s2; m = m2; }
    else ss += s2 * __expf(m2 - m);
  }
  __shared__ float rm[4], rs[4], lsh;
  if (lane == 0) { rm[wave] = m; rs[wave] = ss; }
  __syncthreads();
  if (t == 0) {
    float M = rm[0], S = rs[0];
#pragma unroll
    for (int w = 1; w < 4; w++) {
      float m2 = rm[w], s2 = rs[w];
      if (m2 > M) { S = S * __expf(M - m2) + s2; M = m2; }
      else S += s2 * __expf(m2 - M);
    }
    lsh = M + logf(S);
  }
  __syncthreads();
  float l = lsh;
  float4* po = (float4*)(out + (size_t)bk * LL);
  int start = cx * 1985;
  int end = start + 1985; if (end > LL4) end = LL4;
  for (int idx = start + t; idx < end; idx += 256) {
    float4 v = po[idx];
    v.x -= l; v.y -= l; v.z -= l; v.w -= l;
    po[idx] = v;
  }
}

extern "C" void kernel_launch(void* const* d_in, const int* in_sizes, int n_in,
                              void* d_out, int out_size, void* d_ws, size_t ws_size,
                              hipStream_t stream) {
  const float* hidden = (const float*)d_in[0];
  const int* spans    = (const int*)d_in[1];
  const int* smask    = (const int*)d_in[2];
  const float* W1     = (const float*)d_in[3];
  const float* b1     = (const float*)d_in[4];
  const float* W2     = (const float*)d_in[5];
  const float* b2     = (const float*)d_in[6];
  float* ws = (float*)d_ws;
  unsigned short* AJF  = (unsigned short*)(ws + AJF_OFF);
  unsigned short* AiBh = (unsigned short*)(ws + AIB_OFF);
  const uint4* wfr     = (const uint4*)(ws + W2F_OFF);
  float* part          = ws + PART_OFF;
  float* out = (float*)d_out;

  const int total_pack = NW1F + NW2F + NVBF;
  pack_kernel<<<(total_pack + 255) / 256, 256, 0, stream>>>(W1, W2, hidden, ws);
  gemm1_kernel<<<dim3(25, 8), 256, 0, stream>>>(b1, W1, ws, AJF, AiBh);
  main_kernel<<<dim3(4, 63, NB), 256, 0, stream>>>(AJF, AiBh, wfr, b2, spans, smask, out, part);
  finish_kernel<<<dim3(8, NB * NLAB), 256, 0, stream>>>(part, out);
}